// Round 7
// baseline (410.992 us; speedup 1.0000x reference)
//
#include <hip/hip_runtime.h>
#include <cstdint>

#define NTOK 32768
#define DDIM 256
#define KCB  4096
#define NST 8            // n-splits in tier-2 (512 codes per block)
#define XCAP 8192        // max flagged tokens (expect ~300-1500)
#define MARGIN_U 0.0625f // on u = dot + cc; f16 dot err sigma ~3e-3 -> ~17 sigma net

typedef _Float16 half8 __attribute__((ext_vector_type(8)));
typedef float f32x4 __attribute__((ext_vector_type(4)));
typedef unsigned short ushort_t;

// ---------------------------------------------------------------------------
// helpers
// ---------------------------------------------------------------------------
__device__ __forceinline__ ushort_t f2h(float f, float& back) {
    _Float16 h = (_Float16)f;
    back = (float)h;
    union { _Float16 h; ushort_t u; } c; c.h = h; return c.u;
}
__device__ __forceinline__ short h2s(_Float16 h) {
    union { _Float16 h; short s; } c; c.h = h; return c.s;
}

// ---------------------------------------------------------------------------
// convert embed -> f16 hi/lo + cc[k] = 512 - 0.5*e2[k]; zero worklist counter
// ---------------------------------------------------------------------------
__global__ __launch_bounds__(256) void vq_convert_e(
        const float* __restrict__ embed, ushort_t* __restrict__ hi,
        ushort_t* __restrict__ lo, float* __restrict__ cc,
        int* __restrict__ count) {
    if (blockIdx.x == 0 && threadIdx.x == 0) *count = 0;
    int row = blockIdx.x * 4 + (threadIdx.x >> 6);
    int lane = threadIdx.x & 63;
    size_t off = (size_t)row * DDIM + lane * 4;
    float4 v = *(const float4*)(embed + off);
    float bx, by, bz, bw;
    ushort4 h, l;
    h.x = f2h(v.x, bx); h.y = f2h(v.y, by); h.z = f2h(v.z, bz); h.w = f2h(v.w, bw);
    float t;
    l.x = f2h(v.x - bx, t); l.y = f2h(v.y - by, t);
    l.z = f2h(v.z - bz, t); l.w = f2h(v.w - bw, t);
    *(ushort4*)(hi + off) = h;
    *(ushort4*)(lo + off) = l;
    float s = v.x * v.x + v.y * v.y + v.z * v.z + v.w * v.w;
#pragma unroll
    for (int o = 1; o < 64; o <<= 1) s += __shfl_xor(s, o, 64);
    if (lane == 0) cc[row] = 512.f - 0.5f * s;
}

// ---------------------------------------------------------------------------
// Pass A: 64 tokens x ALL 4096 codes per block (grid 512 = 2 blocks/CU).
// A (x->f16) staged once into 32 KB LDS. B global->VGPR through a ring of 4
// NAMED buffers (in-flight bounded by construction; distance-2 prefetch).
// Barrier-free K-loop. Fused: flagging + worklist + gather of clear winners.
// ---------------------------------------------------------------------------
__global__ __launch_bounds__(256, 2) void vq_pass_a(
        const float* __restrict__ x, const ushort_t* __restrict__ eh,
        const float* __restrict__ cc, const float* __restrict__ embed,
        float* __restrict__ out, int* __restrict__ wl, int* __restrict__ count) {
    __shared__ union U {
        short A[8][64][32];                                   // 32 KB
        struct { float v1[64][2]; int i1[64][2]; float v2[64][2]; } r;
    } sh;
    __shared__ int g_idx[64];
    __shared__ int g_skip[64];

    const int tid = threadIdx.x;
    const int m0 = blockIdx.x * 64;
    const int lane = tid & 63, wv = tid >> 6, wr = wv >> 1, wc = wv & 1;
    const int L15 = lane & 15, quad = lane >> 4;

    // ---- stage A once: x fp32 -> f16 into LDS ----
    {
        const int fr = tid >> 6;          // 0..3
        const int f = tid & 63;           // float4 index within row
        const int akk = f >> 3, aoff = (f & 7) * 4;
#pragma unroll 4
        for (int s = 0; s < 16; ++s) {
            int row = s * 4 + fr;
            float4 v = *(const float4*)(x + (size_t)(m0 + row) * DDIM + f * 4);
            short4 pk = { h2s((_Float16)v.x), h2s((_Float16)v.y),
                          h2s((_Float16)v.z), h2s((_Float16)v.w) };
            *(short4*)(&sh.A[akk][row][aoff]) = pk;
        }
    }
    __syncthreads();
    // barrier-free from here until the final reduction

    // A fragment base: row stride 64 B, kk stride 4096 B (2048 shorts)
    const short* Ab = &sh.A[0][wr * 32 + L15][quad * 8];

    // B row pointers, one per j-column (advanced once per nt)
    const ushort_t* pb0 = eh + (size_t)(wc * 64 + 0 * 16 + L15) * DDIM + quad * 8;
    const ushort_t* pb1 = eh + (size_t)(wc * 64 + 1 * 16 + L15) * DDIM + quad * 8;
    const ushort_t* pb2 = eh + (size_t)(wc * 64 + 2 * 16 + L15) * DDIM + quad * 8;
    const ushort_t* pb3 = eh + (size_t)(wc * 64 + 3 * 16 + L15) * DDIM + quad * 8;
    const float* pc = cc + wc * 64 + L15;

    half8 b0[4], b1[4], b2[4], b3[4];
    auto LB = [&](half8* d, int koff) {
        d[0] = *(const half8*)(pb0 + koff);
        d[1] = *(const half8*)(pb1 + koff);
        d[2] = *(const half8*)(pb2 + koff);
        d[3] = *(const half8*)(pb3 + koff);
    };

    f32x4 acc[2][4];
    auto MStep = [&](int kk, const half8* bb, bool first) {
        half8 a0 = *(const half8*)(Ab + kk * 2048);
        half8 a1 = *(const half8*)(Ab + kk * 2048 + 512);
#pragma unroll
        for (int j = 0; j < 4; ++j) {
            if (first) {
                acc[0][j] = __builtin_amdgcn_mfma_f32_16x16x32_f16(
                    a0, bb[j], (f32x4){0.f, 0.f, 0.f, 0.f}, 0, 0, 0);
                acc[1][j] = __builtin_amdgcn_mfma_f32_16x16x32_f16(
                    a1, bb[j], (f32x4){0.f, 0.f, 0.f, 0.f}, 0, 0, 0);
            } else {
                acc[0][j] = __builtin_amdgcn_mfma_f32_16x16x32_f16(
                    a0, bb[j], acc[0][j], 0, 0, 0);
                acc[1][j] = __builtin_amdgcn_mfma_f32_16x16x32_f16(
                    a1, bb[j], acc[1][j], 0, 0, 0);
            }
        }
    };

    float v1p[8], v2p[8];
#pragma unroll
    for (int s = 0; s < 8; ++s) { v1p[s] = -3.4e38f; v2p[s] = -3.4e38f; }

    LB(b0, 0);
    LB(b1, 32);

#pragma unroll 1
    for (int nt = 0; nt < 32; ++nt) {
        float cc0 = pc[0], cc1 = pc[16], cc2 = pc[32], cc3 = pc[48];
        pc += 128;
        // ring-4, distance-2 prefetch; in-flight bounded by named buffers
        LB(b2, 2 * 32); MStep(0, b0, true);
        LB(b3, 3 * 32); MStep(1, b1, false);
        LB(b0, 4 * 32); MStep(2, b2, false);
        LB(b1, 5 * 32); MStep(3, b3, false);
        LB(b2, 6 * 32); MStep(4, b0, false);
        LB(b3, 7 * 32); MStep(5, b1, false);
        pb0 += 128 * DDIM; pb1 += 128 * DDIM;
        pb2 += 128 * DDIM; pb3 += 128 * DDIM;
        if (nt < 31) LB(b0, 0);
        MStep(6, b2, false);
        if (nt < 31) LB(b1, 32);
        MStep(7, b3, false);

        // packed-index (7-bit) tournament top-2 of u = dot + cc
#pragma unroll
        for (int i = 0; i < 2; ++i)
#pragma unroll
            for (int r = 0; r < 4; ++r) {
                const int slot = i * 4 + r;
                float u0 = acc[i][0][r] + cc0;
                float u1 = acc[i][1][r] + cc1;
                float u2 = acc[i][2][r] + cc2;
                float u3 = acc[i][3][r] + cc3;
                float p0 = __uint_as_float((__float_as_uint(u0) & 0xFFFFFF80u) | (unsigned)(127 - (nt * 4 + 0)));
                float p1 = __uint_as_float((__float_as_uint(u1) & 0xFFFFFF80u) | (unsigned)(127 - (nt * 4 + 1)));
                float p2 = __uint_as_float((__float_as_uint(u2) & 0xFFFFFF80u) | (unsigned)(127 - (nt * 4 + 2)));
                float p3 = __uint_as_float((__float_as_uint(u3) & 0xFFFFFF80u) | (unsigned)(127 - (nt * 4 + 3)));
                float h1 = fmaxf(p0, p1), l1 = fminf(p0, p1);
                float h2 = fmaxf(p2, p3), l2 = fminf(p2, p3);
                float m1 = fmaxf(h1, h2);
                float mm = fminf(h1, h2);
                float m2 = fmaxf(fmaxf(mm, l1), l2);         // v_max3
                float t = fminf(v1p[slot], m1);
                v1p[slot] = fmaxf(v1p[slot], m1);
                v2p[slot] = fmaxf(fmaxf(v2p[slot], t), m2);  // v_max3
            }
    }

    __syncthreads();   // all waves done with sh.A
    // unpack + 16-lane butterfly; rows: wr*32 + i*16 + quad*4 + r
#pragma unroll
    for (int i = 0; i < 2; ++i)
#pragma unroll
        for (int r = 0; r < 4; ++r) {
            const int slot = i * 4 + r;
            unsigned bb = __float_as_uint(v1p[slot]);
            int lin = 127 - (int)(bb & 127u);
            float a1 = v1p[slot];
            int ai = (lin >> 2) * 128 + wc * 64 + (lin & 3) * 16 + L15;
            float a2 = v2p[slot];
#pragma unroll
            for (int off = 1; off < 16; off <<= 1) {
                float o1 = __shfl_xor(a1, off, 64);
                int oi = __shfl_xor(ai, off, 64);
                float o2 = __shfl_xor(a2, off, 64);
                if (o1 > a1 || (o1 == a1 && oi < ai)) {
                    a2 = fmaxf(a1, o2); a1 = o1; ai = oi;
                } else {
                    a2 = fmaxf(a2, o1);
                }
            }
            if (L15 == 0) {
                int lr = wr * 32 + i * 16 + quad * 4 + r;
                sh.r.v1[lr][wc] = a1; sh.r.i1[lr][wc] = ai; sh.r.v2[lr][wc] = a2;
            }
        }
    __syncthreads();
    if (tid < 64) {
        float av1 = sh.r.v1[tid][0]; int ai1 = sh.r.i1[tid][0]; float av2 = sh.r.v2[tid][0];
        float bv1 = sh.r.v1[tid][1]; int bi1 = sh.r.i1[tid][1]; float bv2 = sh.r.v2[tid][1];
        float o1, o2; int oi;
        if (bv1 > av1 || (bv1 == av1 && bi1 < ai1)) { o1 = bv1; oi = bi1; o2 = fmaxf(av1, bv2); }
        else { o1 = av1; oi = ai1; o2 = fmaxf(av2, bv1); }
        bool flag = (o1 - o2 < MARGIN_U);
        int p = 0x7fffffff;
        if (flag) p = atomicAdd(count, 1);
        bool defer = flag && (p < XCAP);
        if (defer) wl[p] = m0 + tid;
        g_idx[tid] = oi;
        g_skip[tid] = defer ? 1 : 0;
    }
    __syncthreads();
    // fused gather for clear winners: wave w writes rows w*16 .. w*16+15
    {
        const int gw = tid >> 6, gl = tid & 63;
#pragma unroll 4
        for (int s = 0; s < 16; ++s) {
            int row = gw * 16 + s;
            if (!g_skip[row]) {
                int idx = g_idx[row];
                float4 val = *(const float4*)(embed + (size_t)idx * DDIM + gl * 4);
                *(float4*)(out + (size_t)(m0 + row) * DDIM + gl * 4) = val;
            }
        }
    }
}

// ---------------------------------------------------------------------------
// Tier-2: 3-pass f16 MFMA rescore, barrier-free K-loop (validated r5/r6).
// Block: 64 flagged tokens x 512 codes (NST=8).
// ---------------------------------------------------------------------------
__global__ __launch_bounds__(256, 2) void vq_rescore_mfma(
        const float* __restrict__ x, const ushort_t* __restrict__ eh,
        const ushort_t* __restrict__ el, const float* __restrict__ cc,
        const int* __restrict__ wl, const int* __restrict__ count,
        float* __restrict__ rv, int* __restrict__ ri) {
    const int cnt = min(*count, XCAP);
    const int m0 = blockIdx.x * 64;
    if (m0 >= cnt) return;
    __shared__ union U {
        struct { short Ah[8][64][32]; short Al[8][64][32]; } t;   // 32+32 KB
        struct { float v1[64][2]; int i1[64][2]; } r;
    } sh;
    const int tid = threadIdx.x;
    const int lane = tid & 63, wv = tid >> 6, wr = wv >> 1, wc = wv & 1;
    const int L15 = lane & 15, quad = lane >> 4;

    // ---- stage A (hi+lo) once ----
    {
        const int fr = tid >> 6;
        const int f = tid & 63;
        const int akk = f >> 3, aoff = (f & 7) * 4;
#pragma unroll 4
        for (int s = 0; s < 16; ++s) {
            int row = s * 4 + fr;
            int t = wl[min(m0 + row, cnt - 1)];
            float4 v = *(const float4*)(x + (size_t)t * DDIM + f * 4);
            float bx, by, bz, bw;
            short4 ph = { (short)f2h(v.x, bx), (short)f2h(v.y, by),
                          (short)f2h(v.z, bz), (short)f2h(v.w, bw) };
            float tt;
            short4 pl = { (short)f2h(v.x - bx, tt), (short)f2h(v.y - by, tt),
                          (short)f2h(v.z - bz, tt), (short)f2h(v.w - bw, tt) };
            *(short4*)(&sh.t.Ah[akk][row][aoff]) = ph;
            *(short4*)(&sh.t.Al[akk][row][aoff]) = pl;
        }
    }
    __syncthreads();

    const unsigned obase = (unsigned)((wc * 64 + L15) * DDIM + quad * 8);
    const unsigned nbase = (unsigned)(blockIdx.y * (KCB / NST) * DDIM);

    float v1[8]; int i1[8];
#pragma unroll
    for (int s = 0; s < 8; ++s) { v1[s] = -3.4e38f; i1[s] = 0; }

#pragma unroll 1
    for (int nt = 0; nt < 4; ++nt) {
        f32x4 acc[2][4];
#pragma unroll 1
        for (int ph = 0; ph < 3; ++ph) {
            const short (*As)[64][32] = (ph < 2) ? sh.t.Ah : sh.t.Al;
            const ushort_t* Bs = (ph == 1) ? el : eh;
            auto loadA = [&](int kk, half8* dst) {
#pragma unroll
                for (int i = 0; i < 2; ++i)
                    dst[i] = *(const half8*)(&As[kk][wr * 32 + i * 16 + L15][quad * 8]);
            };
            auto loadB = [&](int kk, half8* dst) {
                unsigned o = nbase + obase + (unsigned)(nt * 128 * DDIM + kk * 32);
#pragma unroll
                for (int j = 0; j < 4; ++j)
                    dst[j] = *(const half8*)(Bs + o + j * 16 * DDIM);
            };
            half8 a[2][2], b[2][4];
            loadA(0, a[0]); loadB(0, b[0]);
#pragma unroll
            for (int kk = 0; kk < 8; ++kk) {
                const int cur = kk & 1, nxt = cur ^ 1;
                if (kk < 7) { loadB(kk + 1, b[nxt]); loadA(kk + 1, a[nxt]); }
#pragma unroll
                for (int i = 0; i < 2; ++i)
#pragma unroll
                    for (int j = 0; j < 4; ++j) {
                        if (ph == 0 && kk == 0)
                            acc[i][j] = __builtin_amdgcn_mfma_f32_16x16x32_f16(
                                a[cur][i], b[cur][j], (f32x4){0.f, 0.f, 0.f, 0.f}, 0, 0, 0);
                        else
                            acc[i][j] = __builtin_amdgcn_mfma_f32_16x16x32_f16(
                                a[cur][i], b[cur][j], acc[i][j], 0, 0, 0);
                    }
            }
        }
        const int nb = blockIdx.y * (KCB / NST) + nt * 128 + wc * 64 + L15;
#pragma unroll
        for (int j = 0; j < 4; ++j) {
            float ccv = cc[nb + j * 16];
#pragma unroll
            for (int i = 0; i < 2; ++i)
#pragma unroll
                for (int r = 0; r < 4; ++r) {
                    const int slot = i * 4 + r;
                    float u = acc[i][j][r] + ccv;
                    int n = nb + j * 16;
                    if (u > v1[slot]) { v1[slot] = u; i1[slot] = n; }
                }
        }
    }
    __syncthreads();
#pragma unroll
    for (int i = 0; i < 2; ++i)
#pragma unroll
        for (int r = 0; r < 4; ++r) {
            const int slot = i * 4 + r;
            float a1 = v1[slot]; int ai = i1[slot];
#pragma unroll
            for (int off = 1; off < 16; off <<= 1) {
                float o1 = __shfl_xor(a1, off, 64);
                int oi = __shfl_xor(ai, off, 64);
                if (o1 > a1 || (o1 == a1 && oi < ai)) { a1 = o1; ai = oi; }
            }
            if (L15 == 0) {
                int lr = wr * 32 + i * 16 + quad * 4 + r;
                sh.r.v1[lr][wc] = a1; sh.r.i1[lr][wc] = ai;
            }
        }
    __syncthreads();
    if (tid < 64 && m0 + tid < cnt) {
        float av1 = sh.r.v1[tid][0]; int ai1 = sh.r.i1[tid][0];
        float bv1 = sh.r.v1[tid][1]; int bi1 = sh.r.i1[tid][1];
        float o1; int oi;
        if (bv1 > av1 || (bv1 == av1 && bi1 < ai1)) { o1 = bv1; oi = bi1; }
        else { o1 = av1; oi = ai1; }
        size_t o = (size_t)(m0 + tid) * NST + blockIdx.y;
        rv[o] = o1; ri[o] = oi;
    }
}

// ---------------------------------------------------------------------------
// merge tier-2 slices + gather for flagged tokens (one wave per token)
// ---------------------------------------------------------------------------
__global__ __launch_bounds__(256) void vq_merge2_gather(
        const int* __restrict__ wl, const int* __restrict__ count,
        const float* __restrict__ rv, const int* __restrict__ ri,
        const float* __restrict__ embed, float* __restrict__ out) {
    int wave = threadIdx.x >> 6, lane = threadIdx.x & 63;
    int wi = blockIdx.x * 4 + wave;
    int cnt = min(*count, XCAP);
    if (wi >= cnt) return;
    float v1 = -3.4e38f; int i1 = 0x7fffffff;
    if (lane < NST) {
        size_t o = (size_t)wi * NST + lane;
        v1 = rv[o]; i1 = ri[o];
    }
#pragma unroll
    for (int off = 1; off < NST; off <<= 1) {
        float o1 = __shfl_xor(v1, off, 64);
        int oi = __shfl_xor(i1, off, 64);
        if (o1 > v1 || (o1 == v1 && oi < i1)) { v1 = o1; i1 = oi; }
    }
    int idx = __shfl(i1, 0, 64);
    int t = wl[wi];
    const float4* src = (const float4*)(embed + (size_t)idx * DDIM);
    float4* dst = (float4*)(out + (size_t)t * DDIM);
    dst[lane] = src[lane];
}

// ===========================================================================
// Fallback fp32 path (round-1, validated) for small workspace
// ===========================================================================
#define TMF 128
#define DCF 32
#define LSF 132
#define KSPLITF 4
#define KPERF (KCB / KSPLITF)

__global__ __launch_bounds__(256) void vq_e2_fp32(const float* __restrict__ embed,
                                                  float* __restrict__ e2) {
    int k = blockIdx.x * blockDim.x + threadIdx.x;
    if (k >= KCB) return;
    const float4* row = (const float4*)(embed + (size_t)k * DDIM);
    float s = 0.f;
#pragma unroll
    for (int i = 0; i < DDIM / 4; ++i) {
        float4 v = row[i];
        s += v.x * v.x + v.y * v.y + v.z * v.z + v.w * v.w;
    }
    e2[k] = s;
}

__global__ __launch_bounds__(256, 3) void vq_main_fp32(
        const float* __restrict__ x, const float* __restrict__ embed,
        const float* __restrict__ e2,
        float* __restrict__ bestv, int* __restrict__ besti) {
    __shared__ union U {
        struct { float xs[DCF][LSF]; float es[DCF][LSF]; } t;
        struct { float v[TMF][16]; int i[TMF][16]; } r;
    } sh;
    const int tid = threadIdx.x;
    const int tx = tid & 15, ty = tid >> 4;
    const int m0 = blockIdx.x * TMF;
    const int kbase = blockIdx.y * KPERF;
    const int srow = tid >> 3, sd4 = (tid & 7) * 4;
    float bv[2][4]; int bi[2][4];
#pragma unroll
    for (int a = 0; a < 2; ++a)
#pragma unroll
        for (int b = 0; b < 4; ++b) { bv[a][b] = 3.4e38f; bi[a][b] = 0; }
    for (int kt = 0; kt < KPERF / 128; ++kt) {
        const int k0 = kbase + kt * 128;
        float acc[2][4][2][4];
#pragma unroll
        for (int a = 0; a < 2; ++a)
#pragma unroll
            for (int b = 0; b < 4; ++b)
#pragma unroll
                for (int c = 0; c < 2; ++c)
#pragma unroll
                    for (int e = 0; e < 4; ++e) acc[a][b][c][e] = 0.f;
        for (int dc = 0; dc < DDIM / DCF; ++dc) {
#pragma unroll
            for (int p = 0; p < 4; ++p) {
                int m = p * 32 + srow;
                float4 v = *(const float4*)(x + (size_t)(m0 + m) * DDIM + dc * DCF + sd4);
                sh.t.xs[sd4 + 0][m] = v.x; sh.t.xs[sd4 + 1][m] = v.y;
                sh.t.xs[sd4 + 2][m] = v.z; sh.t.xs[sd4 + 3][m] = v.w;
                float4 w = *(const float4*)(embed + (size_t)(k0 + m) * DDIM + dc * DCF + sd4);
                sh.t.es[sd4 + 0][m] = w.x; sh.t.es[sd4 + 1][m] = w.y;
                sh.t.es[sd4 + 2][m] = w.z; sh.t.es[sd4 + 3][m] = w.w;
            }
            __syncthreads();
#pragma unroll 8
            for (int d = 0; d < DCF; ++d) {
                float4 xa0 = *(const float4*)&sh.t.xs[d][ty * 4];
                float4 xa1 = *(const float4*)&sh.t.xs[d][ty * 4 + 64];
                float4 eb0 = *(const float4*)&sh.t.es[d][tx * 4];
                float4 eb1 = *(const float4*)&sh.t.es[d][tx * 4 + 64];
                float xr[2][4] = {{xa0.x, xa0.y, xa0.z, xa0.w}, {xa1.x, xa1.y, xa1.z, xa1.w}};
                float er[2][4] = {{eb0.x, eb0.y, eb0.z, eb0.w}, {eb1.x, eb1.y, eb1.z, eb1.w}};
#pragma unroll
                for (int a = 0; a < 2; ++a)
#pragma unroll
                    for (int b = 0; b < 4; ++b)
#pragma unroll
                        for (int c = 0; c < 2; ++c)
#pragma unroll
                            for (int e = 0; e < 4; ++e)
                                acc[a][b][c][e] += xr[a][b] * er[c][e];
            }
            __syncthreads();
        }
#pragma unroll
        for (int c = 0; c < 2; ++c)
#pragma unroll
            for (int e = 0; e < 4; ++e) {
                int k = k0 + c * 64 + tx * 4 + e;
                float ek = e2[k];
#pragma unroll
                for (int a = 0; a < 2; ++a)
#pragma unroll
                    for (int b = 0; b < 4; ++b) {
                        float s = ek - 2.f * acc[a][b][c][e];
                        if (s < bv[a][b]) { bv[a][b] = s; bi[a][b] = k; }
                    }
            }
    }
    __syncthreads();
#pragma unroll
    for (int a = 0; a < 2; ++a)
#pragma unroll
        for (int b = 0; b < 4; ++b) {
            int row = a * 64 + ty * 4 + b;
            sh.r.v[row][tx] = bv[a][b]; sh.r.i[row][tx] = bi[a][b];
        }
    __syncthreads();
    if (tid < TMF) {
        float best = sh.r.v[tid][0]; int idx = sh.r.i[tid][0];
#pragma unroll
        for (int j = 1; j < 16; ++j) {
            float v = sh.r.v[tid][j]; int ii = sh.r.i[tid][j];
            if (v < best || (v == best && ii < idx)) { best = v; idx = ii; }
        }
        bestv[(size_t)blockIdx.y * NTOK + m0 + tid] = best;
        besti[(size_t)blockIdx.y * NTOK + m0 + tid] = idx;
    }
}

__global__ __launch_bounds__(256) void vq_gather_fp32(
        const float* __restrict__ embed, const float* __restrict__ bestv,
        const int* __restrict__ besti, float* __restrict__ out) {
    int token = blockIdx.x * 4 + (threadIdx.x >> 6);
    int lane = threadIdx.x & 63;
    float best = bestv[token]; int idx = besti[token];
#pragma unroll
    for (int s = 1; s < KSPLITF; ++s) {
        float v = bestv[(size_t)s * NTOK + token];
        int ii = besti[(size_t)s * NTOK + token];
        if (v < best || (v == best && ii < idx)) { best = v; idx = ii; }
    }
    const float4* src = (const float4*)(embed + (size_t)idx * DDIM);
    float4* dst = (float4*)(out + (size_t)token * DDIM);
    dst[lane] = src[lane];
}

// ===========================================================================
extern "C" void kernel_launch(void* const* d_in, const int* in_sizes, int n_in,
                              void* d_out, int out_size, void* d_ws, size_t ws_size,
                              hipStream_t stream) {
    (void)in_sizes; (void)n_in; (void)out_size;
    const float* x = (const float*)d_in[0];
    const float* embed = (const float*)d_in[1];
    float* out = (float*)d_out;

    char* w = (char*)d_ws;
    auto carve = [&](size_t bytes) { char* p = w; w += (bytes + 255) & ~(size_t)255; return p; };

    const size_t sz_eh = (size_t)KCB * DDIM * 2;           // 2 MB
    const size_t need = 2 * sz_eh + KCB * 4 + (size_t)XCAP * 4 +
                        2 * (size_t)XCAP * NST * 4 + 8192;

    if (ws_size >= need) {
        ushort_t* eh = (ushort_t*)carve(sz_eh);
        ushort_t* el = (ushort_t*)carve(sz_eh);
        float* cc = (float*)carve(KCB * 4);
        int* wl = (int*)carve((size_t)XCAP * 4);
        float* rv = (float*)carve((size_t)XCAP * NST * 4);
        int* ri = (int*)carve((size_t)XCAP * NST * 4);
        int* count = (int*)carve(256);

        vq_convert_e<<<KCB / 4, 256, 0, stream>>>(embed, eh, el, cc, count);
        vq_pass_a<<<NTOK / 64, 256, 0, stream>>>(x, eh, cc, embed, out, wl, count);
        vq_rescore_mfma<<<dim3(XCAP / 64, NST), 256, 0, stream>>>(
            x, eh, el, cc, wl, count, rv, ri);
        vq_merge2_gather<<<XCAP / 4, 256, 0, stream>>>(wl, count, rv, ri, embed, out);
    } else {
        float* e2 = (float*)carve(KCB * 4);
        float* bestv = (float*)carve((size_t)KSPLITF * NTOK * 4);
        int* besti = (int*)carve((size_t)KSPLITF * NTOK * 4);
        vq_e2_fp32<<<KCB / 256, 256, 0, stream>>>(embed, e2);
        vq_main_fp32<<<dim3(NTOK / TMF, KSPLITF), 256, 0, stream>>>(x, embed, e2, bestv, besti);
        vq_gather_fp32<<<NTOK / 4, 256, 0, stream>>>(embed, bestv, besti, out);
    }
}

// Round 8
// 386.561 us; speedup vs baseline: 1.0632x; 1.0632x over previous
//
#include <hip/hip_runtime.h>
#include <cstdint>

#define NTOK 32768
#define DDIM 256
#define KCB  4096
#define NSA 2            // n-splits in pass A (2048 codes per block)
#define NTI 16           // n-tiles per block (128 codes each)
#define NST 8            // n-splits in tier-2 (512 codes per block)
#define XCAP 8192        // max flagged tokens
#define MARGIN_U 0.0625f // on u = dot + cc (validated r7)

typedef _Float16 half8 __attribute__((ext_vector_type(8)));
typedef float f32x4 __attribute__((ext_vector_type(4)));
typedef unsigned short ushort_t;

// ---------------------------------------------------------------------------
// helpers
// ---------------------------------------------------------------------------
__device__ __forceinline__ ushort_t f2h(float f, float& back) {
    _Float16 h = (_Float16)f;
    back = (float)h;
    union { _Float16 h; ushort_t u; } c; c.h = h; return c.u;
}
__device__ __forceinline__ short h2s(_Float16 h) {
    union { _Float16 h; short s; } c; c.h = h; return c.s;
}
__device__ __forceinline__ void gload_lds16(const void* g, void* l) {
    __builtin_amdgcn_global_load_lds(
        (const __attribute__((address_space(1))) void*)g,
        (__attribute__((address_space(3))) void*)l, 16, 0, 0);
}

// ---------------------------------------------------------------------------
// convert embed -> f16 hi/lo + cc[k] = 512 - 0.5*e2[k]; zero worklist counter
// ---------------------------------------------------------------------------
__global__ __launch_bounds__(256) void vq_convert_e(
        const float* __restrict__ embed, ushort_t* __restrict__ hi,
        ushort_t* __restrict__ lo, float* __restrict__ cc,
        int* __restrict__ count) {
    if (blockIdx.x == 0 && threadIdx.x == 0) *count = 0;
    int row = blockIdx.x * 4 + (threadIdx.x >> 6);
    int lane = threadIdx.x & 63;
    size_t off = (size_t)row * DDIM + lane * 4;
    float4 v = *(const float4*)(embed + off);
    float bx, by, bz, bw;
    ushort4 h, l;
    h.x = f2h(v.x, bx); h.y = f2h(v.y, by); h.z = f2h(v.z, bz); h.w = f2h(v.w, bw);
    float t;
    l.x = f2h(v.x - bx, t); l.y = f2h(v.y - by, t);
    l.z = f2h(v.z - bz, t); l.w = f2h(v.w - bw, t);
    *(ushort4*)(hi + off) = h;
    *(ushort4*)(lo + off) = l;
    float s = v.x * v.x + v.y * v.y + v.z * v.z + v.w * v.w;
#pragma unroll
    for (int o = 1; o < 64; o <<= 1) s += __shfl_xor(s, o, 64);
    if (lane == 0) cc[row] = 512.f - 0.5f * s;
}

// ---------------------------------------------------------------------------
// Pass A: 128 tokens x 2048 codes (grid (256,2) = 2 blocks/CU).
// A (x->f16) held in 128 persistent VGPRs per lane (full K=256 wave slice).
// B staged per-kk via global_load_lds double-buffer, ONE barrier per step.
// Epilogue: 6-bit packed-index tournament top-2 of u = dot + cc.
// ---------------------------------------------------------------------------
__global__ __launch_bounds__(256, 2) void vq_pass_a(
        const float* __restrict__ x, const ushort_t* __restrict__ eh,
        const float* __restrict__ cc,
        float* __restrict__ gv1, int* __restrict__ gi1, float* __restrict__ gv2) {
    __shared__ union U {
        short B[2][128][32];                                  // 16 KB dbuf
        struct { float v1[128][2]; int i1[128][2]; float v2[128][2]; } r;
    } sh;
    const int tid = threadIdx.x;
    const int m0 = blockIdx.x * 128;
    const int kbase = blockIdx.y * (KCB / NSA);
    const int lane = tid & 63, wv = tid >> 6, wr = wv >> 1, wc = wv & 1;
    const int L15 = lane & 15, quad = lane >> 4;

    // ---- load A into registers: stage chunks through B[0], read frags ----
    half8 Areg[8][4];
    {
        const int row = tid >> 1;            // 0..127
        const int h16 = (tid & 1) * 16;      // 16-dim half of the 32-chunk
#pragma unroll 1
        for (int kk = 0; kk < 8; ++kk) {
            __syncthreads();                 // prior frag reads done
#pragma unroll
            for (int c = 0; c < 4; ++c) {
                float4 v = *(const float4*)(x + (size_t)(m0 + row) * DDIM + kk * 32 + h16 + c * 4);
                short4 pk = { h2s((_Float16)v.x), h2s((_Float16)v.y),
                              h2s((_Float16)v.z), h2s((_Float16)v.w) };
                *(short4*)(&sh.B[0][row][h16 + c * 4]) = pk;
            }
            __syncthreads();
#pragma unroll
            for (int i = 0; i < 4; ++i)
                Areg[kk][i] = *(const half8*)(&sh.B[0][wr * 64 + i * 16 + L15][quad * 8]);
        }
    }
    __syncthreads();   // all frag reads done before B staging overwrites

    // ---- B staging mapping (global_load_lds width 16) ----
    const int ca0 = tid, ca1 = 256 + tid;
    const int brow0 = ca0 >> 2, bq0 = ca0 & 3;
    const int brow1 = ca1 >> 2, bq1 = ca1 & 3;
    const ushort_t* ebase = eh + (size_t)kbase * DDIM;
    auto stageB = [&](int it) {      // it in [0, NTI*8)
        int nt = it >> 3, kk = it & 7;
        short* base = &sh.B[it & 1][0][0];
        gload_lds16(ebase + (size_t)(nt * 128 + brow0) * DDIM + kk * 32 + bq0 * 8, base + ca0 * 8);
        gload_lds16(ebase + (size_t)(nt * 128 + brow1) * DDIM + kk * 32 + bq1 * 8, base + ca1 * 8);
    };
    stageB(0);

    const float* pc = cc + kbase + wc * 64 + L15;
    float v1p[16], v2p[16];
#pragma unroll
    for (int s = 0; s < 16; ++s) { v1p[s] = -3.4e38f; v2p[s] = -3.4e38f; }

    f32x4 acc[4][4];
#pragma unroll 1
    for (int nt = 0; nt < NTI; ++nt) {
        float cc0 = pc[0], cc1 = pc[16], cc2 = pc[32], cc3 = pc[48];
        pc += 128;
#pragma unroll
        for (int kk = 0; kk < 8; ++kk) {
            __syncthreads();         // drains stage(it) issued one compute-phase ago
            if (kk < 7) stageB(nt * 8 + kk + 1);
            else if (nt < NTI - 1) stageB(nt * 8 + 8);
            const short* Bf = &sh.B[kk & 1][0][0] + (wc * 64 + L15) * 32 + quad * 8;
#pragma unroll
            for (int j = 0; j < 4; ++j) {
                half8 bj = *(const half8*)(Bf + j * 16 * 32);
#pragma unroll
                for (int i = 0; i < 4; ++i) {
                    if (kk == 0)
                        acc[i][j] = __builtin_amdgcn_mfma_f32_16x16x32_f16(
                            Areg[0][i], bj, (f32x4){0.f, 0.f, 0.f, 0.f}, 0, 0, 0);
                    else
                        acc[i][j] = __builtin_amdgcn_mfma_f32_16x16x32_f16(
                            Areg[kk][i], bj, acc[i][j], 0, 0, 0);
                }
            }
        }
        // 6-bit packed-index tournament top-2 of u = dot + cc
        const unsigned inv0 = (unsigned)(63 - nt * 4);
#pragma unroll
        for (int i = 0; i < 4; ++i)
#pragma unroll
            for (int r = 0; r < 4; ++r) {
                const int slot = i * 4 + r;
                float u0 = acc[i][0][r] + cc0;
                float u1 = acc[i][1][r] + cc1;
                float u2 = acc[i][2][r] + cc2;
                float u3 = acc[i][3][r] + cc3;
                float p0 = __uint_as_float((__float_as_uint(u0) & 0xFFFFFFC0u) | inv0);
                float p1 = __uint_as_float((__float_as_uint(u1) & 0xFFFFFFC0u) | (inv0 - 1));
                float p2 = __uint_as_float((__float_as_uint(u2) & 0xFFFFFFC0u) | (inv0 - 2));
                float p3 = __uint_as_float((__float_as_uint(u3) & 0xFFFFFFC0u) | (inv0 - 3));
                float h1 = fmaxf(p0, p1), l1 = fminf(p0, p1);
                float h2 = fmaxf(p2, p3), l2 = fminf(p2, p3);
                float m1 = fmaxf(h1, h2);
                float mm = fminf(h1, h2);
                float m2 = fmaxf(fmaxf(mm, l1), l2);         // v_max3
                float t = fminf(v1p[slot], m1);
                v1p[slot] = fmaxf(v1p[slot], m1);
                v2p[slot] = fmaxf(fmaxf(v2p[slot], t), m2);  // v_max3
            }
    }

    __syncthreads();   // done with sh.B before reduction reuse
#pragma unroll
    for (int i = 0; i < 4; ++i)
#pragma unroll
        for (int r = 0; r < 4; ++r) {
            const int slot = i * 4 + r;
            unsigned b1 = __float_as_uint(v1p[slot]);
            int lin = 63 - (int)(b1 & 63u);
            float a1 = v1p[slot];
            int ai = kbase + (lin >> 2) * 128 + wc * 64 + (lin & 3) * 16 + L15;
            float a2 = v2p[slot];
#pragma unroll
            for (int off = 1; off < 16; off <<= 1) {
                float o1 = __shfl_xor(a1, off, 64);
                int oi = __shfl_xor(ai, off, 64);
                float o2 = __shfl_xor(a2, off, 64);
                if (o1 > a1 || (o1 == a1 && oi < ai)) {
                    a2 = fmaxf(a1, o2); a1 = o1; ai = oi;
                } else {
                    a2 = fmaxf(a2, o1);
                }
            }
            if (L15 == 0) {
                int lr = wr * 64 + i * 16 + quad * 4 + r;
                sh.r.v1[lr][wc] = a1; sh.r.i1[lr][wc] = ai; sh.r.v2[lr][wc] = a2;
            }
        }
    __syncthreads();
    if (tid < 128) {
        float av1 = sh.r.v1[tid][0]; int ai1 = sh.r.i1[tid][0]; float av2 = sh.r.v2[tid][0];
        float bv1 = sh.r.v1[tid][1]; int bi1 = sh.r.i1[tid][1]; float bv2 = sh.r.v2[tid][1];
        float o1, o2; int oi;
        if (bv1 > av1 || (bv1 == av1 && bi1 < ai1)) { o1 = bv1; oi = bi1; o2 = fmaxf(av1, bv2); }
        else { o1 = av1; oi = ai1; o2 = fmaxf(av2, bv1); }
        size_t o = (size_t)(m0 + tid) * NSA + blockIdx.y;
        gv1[o] = o1; gi1[o] = oi; gv2[o] = o2;
    }
}

// ---------------------------------------------------------------------------
// merge NSA slices per token; gather clear winners; flag small-gap tokens
// ---------------------------------------------------------------------------
__global__ __launch_bounds__(256) void vq_merge_gather(
        const float* __restrict__ gv1, const int* __restrict__ gi1,
        const float* __restrict__ gv2, const float* __restrict__ embed,
        float* __restrict__ out, int* __restrict__ wl, int* __restrict__ count) {
    int wave = threadIdx.x >> 6, lane = threadIdx.x & 63;
    int t = blockIdx.x * 4 + wave;
    float v1 = -3.4e38f, v2 = -3.4e38f; int i1 = 0x7fffffff;
    if (lane < NSA) {
        size_t o = (size_t)t * NSA + lane;
        v1 = gv1[o]; i1 = gi1[o]; v2 = gv2[o];
    }
#pragma unroll
    for (int off = 1; off < NSA; off <<= 1) {
        float o1 = __shfl_xor(v1, off, 64);
        int oi = __shfl_xor(i1, off, 64);
        float o2 = __shfl_xor(v2, off, 64);
        if (o1 > v1 || (o1 == v1 && oi < i1)) { v2 = fmaxf(v1, o2); v1 = o1; i1 = oi; }
        else v2 = fmaxf(v2, o1);
    }
    int flag = __shfl((v1 - v2 < MARGIN_U) ? 1 : 0, 0, 64);
    int idx = __shfl(i1, 0, 64);
    int p = 0x7fffffff;
    if (flag && lane == 0) p = atomicAdd(count, 1);
    p = __shfl(p, 0, 64);
    if (flag && p < XCAP) {
        if (lane == 0) wl[p] = t;
    } else {
        const float4* src = (const float4*)(embed + (size_t)idx * DDIM);
        float4* dst = (float4*)(out + (size_t)t * DDIM);
        dst[lane] = src[lane];
    }
}

// ---------------------------------------------------------------------------
// Tier-2: 3-pass f16 MFMA rescore, barrier-free K-loop (validated r5-r7).
// Block: 64 flagged tokens x 512 codes (NST=8).
// ---------------------------------------------------------------------------
__global__ __launch_bounds__(256, 2) void vq_rescore_mfma(
        const float* __restrict__ x, const ushort_t* __restrict__ eh,
        const ushort_t* __restrict__ el, const float* __restrict__ cc,
        const int* __restrict__ wl, const int* __restrict__ count,
        float* __restrict__ rv, int* __restrict__ ri) {
    const int cnt = min(*count, XCAP);
    const int m0 = blockIdx.x * 64;
    if (m0 >= cnt) return;
    __shared__ union U {
        struct { short Ah[8][64][32]; short Al[8][64][32]; } t;   // 32+32 KB
        struct { float v1[64][2]; int i1[64][2]; } r;
    } sh;
    const int tid = threadIdx.x;
    const int lane = tid & 63, wv = tid >> 6, wr = wv >> 1, wc = wv & 1;
    const int L15 = lane & 15, quad = lane >> 4;

    // ---- stage A (hi+lo) once ----
    {
        const int fr = tid >> 6;
        const int f = tid & 63;
        const int akk = f >> 3, aoff = (f & 7) * 4;
#pragma unroll 4
        for (int s = 0; s < 16; ++s) {
            int row = s * 4 + fr;
            int t = wl[min(m0 + row, cnt - 1)];
            float4 v = *(const float4*)(x + (size_t)t * DDIM + f * 4);
            float bx, by, bz, bw;
            short4 ph = { (short)f2h(v.x, bx), (short)f2h(v.y, by),
                          (short)f2h(v.z, bz), (short)f2h(v.w, bw) };
            float tt;
            short4 pl = { (short)f2h(v.x - bx, tt), (short)f2h(v.y - by, tt),
                          (short)f2h(v.z - bz, tt), (short)f2h(v.w - bw, tt) };
            *(short4*)(&sh.t.Ah[akk][row][aoff]) = ph;
            *(short4*)(&sh.t.Al[akk][row][aoff]) = pl;
        }
    }
    __syncthreads();

    const unsigned obase = (unsigned)((wc * 64 + L15) * DDIM + quad * 8);
    const unsigned nbase = (unsigned)(blockIdx.y * (KCB / NST) * DDIM);

    float v1[8]; int i1[8];
#pragma unroll
    for (int s = 0; s < 8; ++s) { v1[s] = -3.4e38f; i1[s] = 0; }

#pragma unroll 1
    for (int nt = 0; nt < 4; ++nt) {
        f32x4 acc[2][4];
#pragma unroll 1
        for (int ph = 0; ph < 3; ++ph) {
            const short (*As)[64][32] = (ph < 2) ? sh.t.Ah : sh.t.Al;
            const ushort_t* Bs = (ph == 1) ? el : eh;
            auto loadA = [&](int kk, half8* dst) {
#pragma unroll
                for (int i = 0; i < 2; ++i)
                    dst[i] = *(const half8*)(&As[kk][wr * 32 + i * 16 + L15][quad * 8]);
            };
            auto loadB = [&](int kk, half8* dst) {
                unsigned o = nbase + obase + (unsigned)(nt * 128 * DDIM + kk * 32);
#pragma unroll
                for (int j = 0; j < 4; ++j)
                    dst[j] = *(const half8*)(Bs + o + j * 16 * DDIM);
            };
            half8 a[2][2], b[2][4];
            loadA(0, a[0]); loadB(0, b[0]);
#pragma unroll
            for (int kk = 0; kk < 8; ++kk) {
                const int cur = kk & 1, nxt = cur ^ 1;
                if (kk < 7) { loadB(kk + 1, b[nxt]); loadA(kk + 1, a[nxt]); }
#pragma unroll
                for (int i = 0; i < 2; ++i)
#pragma unroll
                    for (int j = 0; j < 4; ++j) {
                        if (ph == 0 && kk == 0)
                            acc[i][j] = __builtin_amdgcn_mfma_f32_16x16x32_f16(
                                a[cur][i], b[cur][j], (f32x4){0.f, 0.f, 0.f, 0.f}, 0, 0, 0);
                        else
                            acc[i][j] = __builtin_amdgcn_mfma_f32_16x16x32_f16(
                                a[cur][i], b[cur][j], acc[i][j], 0, 0, 0);
                    }
            }
        }
        const int nb = blockIdx.y * (KCB / NST) + nt * 128 + wc * 64 + L15;
#pragma unroll
        for (int j = 0; j < 4; ++j) {
            float ccv = cc[nb + j * 16];
#pragma unroll
            for (int i = 0; i < 2; ++i)
#pragma unroll
                for (int r = 0; r < 4; ++r) {
                    const int slot = i * 4 + r;
                    float u = acc[i][j][r] + ccv;
                    int n = nb + j * 16;
                    if (u > v1[slot]) { v1[slot] = u; i1[slot] = n; }
                }
        }
    }
    __syncthreads();
#pragma unroll
    for (int i = 0; i < 2; ++i)
#pragma unroll
        for (int r = 0; r < 4; ++r) {
            const int slot = i * 4 + r;
            float a1 = v1[slot]; int ai = i1[slot];
#pragma unroll
            for (int off = 1; off < 16; off <<= 1) {
                float o1 = __shfl_xor(a1, off, 64);
                int oi = __shfl_xor(ai, off, 64);
                if (o1 > a1 || (o1 == a1 && oi < ai)) { a1 = o1; ai = oi; }
            }
            if (L15 == 0) {
                int lr = wr * 32 + i * 16 + quad * 4 + r;
                sh.r.v1[lr][wc] = a1; sh.r.i1[lr][wc] = ai;
            }
        }
    __syncthreads();
    if (tid < 64 && m0 + tid < cnt) {
        float av1 = sh.r.v1[tid][0]; int ai1 = sh.r.i1[tid][0];
        float bv1 = sh.r.v1[tid][1]; int bi1 = sh.r.i1[tid][1];
        float o1; int oi;
        if (bv1 > av1 || (bv1 == av1 && bi1 < ai1)) { o1 = bv1; oi = bi1; }
        else { o1 = av1; oi = ai1; }
        size_t o = (size_t)(m0 + tid) * NST + blockIdx.y;
        rv[o] = o1; ri[o] = oi;
    }
}

// ---------------------------------------------------------------------------
// merge tier-2 slices + gather for flagged tokens (one wave per token)
// ---------------------------------------------------------------------------
__global__ __launch_bounds__(256) void vq_merge2_gather(
        const int* __restrict__ wl, const int* __restrict__ count,
        const float* __restrict__ rv, const int* __restrict__ ri,
        const float* __restrict__ embed, float* __restrict__ out) {
    int wave = threadIdx.x >> 6, lane = threadIdx.x & 63;
    int wi = blockIdx.x * 4 + wave;
    int cnt = min(*count, XCAP);
    if (wi >= cnt) return;
    float v1 = -3.4e38f; int i1 = 0x7fffffff;
    if (lane < NST) {
        size_t o = (size_t)wi * NST + lane;
        v1 = rv[o]; i1 = ri[o];
    }
#pragma unroll
    for (int off = 1; off < NST; off <<= 1) {
        float o1 = __shfl_xor(v1, off, 64);
        int oi = __shfl_xor(i1, off, 64);
        if (o1 > v1 || (o1 == v1 && oi < i1)) { v1 = o1; i1 = oi; }
    }
    int idx = __shfl(i1, 0, 64);
    int t = wl[wi];
    const float4* src = (const float4*)(embed + (size_t)idx * DDIM);
    float4* dst = (float4*)(out + (size_t)t * DDIM);
    dst[lane] = src[lane];
}

// ===========================================================================
// Fallback fp32 path (round-1, validated) for small workspace
// ===========================================================================
#define TMF 128
#define DCF 32
#define LSF 132
#define KSPLITF 4
#define KPERF (KCB / KSPLITF)

__global__ __launch_bounds__(256) void vq_e2_fp32(const float* __restrict__ embed,
                                                  float* __restrict__ e2) {
    int k = blockIdx.x * blockDim.x + threadIdx.x;
    if (k >= KCB) return;
    const float4* row = (const float4*)(embed + (size_t)k * DDIM);
    float s = 0.f;
#pragma unroll
    for (int i = 0; i < DDIM / 4; ++i) {
        float4 v = row[i];
        s += v.x * v.x + v.y * v.y + v.z * v.z + v.w * v.w;
    }
    e2[k] = s;
}

__global__ __launch_bounds__(256, 3) void vq_main_fp32(
        const float* __restrict__ x, const float* __restrict__ embed,
        const float* __restrict__ e2,
        float* __restrict__ bestv, int* __restrict__ besti) {
    __shared__ union U {
        struct { float xs[DCF][LSF]; float es[DCF][LSF]; } t;
        struct { float v[TMF][16]; int i[TMF][16]; } r;
    } sh;
    const int tid = threadIdx.x;
    const int tx = tid & 15, ty = tid >> 4;
    const int m0 = blockIdx.x * TMF;
    const int kbase = blockIdx.y * KPERF;
    const int srow = tid >> 3, sd4 = (tid & 7) * 4;
    float bv[2][4]; int bi[2][4];
#pragma unroll
    for (int a = 0; a < 2; ++a)
#pragma unroll
        for (int b = 0; b < 4; ++b) { bv[a][b] = 3.4e38f; bi[a][b] = 0; }
    for (int kt = 0; kt < KPERF / 128; ++kt) {
        const int k0 = kbase + kt * 128;
        float acc[2][4][2][4];
#pragma unroll
        for (int a = 0; a < 2; ++a)
#pragma unroll
            for (int b = 0; b < 4; ++b)
#pragma unroll
                for (int c = 0; c < 2; ++c)
#pragma unroll
                    for (int e = 0; e < 4; ++e) acc[a][b][c][e] = 0.f;
        for (int dc = 0; dc < DDIM / DCF; ++dc) {
#pragma unroll
            for (int p = 0; p < 4; ++p) {
                int m = p * 32 + srow;
                float4 v = *(const float4*)(x + (size_t)(m0 + m) * DDIM + dc * DCF + sd4);
                sh.t.xs[sd4 + 0][m] = v.x; sh.t.xs[sd4 + 1][m] = v.y;
                sh.t.xs[sd4 + 2][m] = v.z; sh.t.xs[sd4 + 3][m] = v.w;
                float4 w = *(const float4*)(embed + (size_t)(k0 + m) * DDIM + dc * DCF + sd4);
                sh.t.es[sd4 + 0][m] = w.x; sh.t.es[sd4 + 1][m] = w.y;
                sh.t.es[sd4 + 2][m] = w.z; sh.t.es[sd4 + 3][m] = w.w;
            }
            __syncthreads();
#pragma unroll 8
            for (int d = 0; d < DCF; ++d) {
                float4 xa0 = *(const float4*)&sh.t.xs[d][ty * 4];
                float4 xa1 = *(const float4*)&sh.t.xs[d][ty * 4 + 64];
                float4 eb0 = *(const float4*)&sh.t.es[d][tx * 4];
                float4 eb1 = *(const float4*)&sh.t.es[d][tx * 4 + 64];
                float xr[2][4] = {{xa0.x, xa0.y, xa0.z, xa0.w}, {xa1.x, xa1.y, xa1.z, xa1.w}};
                float er[2][4] = {{eb0.x, eb0.y, eb0.z, eb0.w}, {eb1.x, eb1.y, eb1.z, eb1.w}};
#pragma unroll
                for (int a = 0; a < 2; ++a)
#pragma unroll
                    for (int b = 0; b < 4; ++b)
#pragma unroll
                        for (int c = 0; c < 2; ++c)
#pragma unroll
                            for (int e = 0; e < 4; ++e)
                                acc[a][b][c][e] += xr[a][b] * er[c][e];
            }
            __syncthreads();
        }
#pragma unroll
        for (int c = 0; c < 2; ++c)
#pragma unroll
            for (int e = 0; e < 4; ++e) {
                int k = k0 + c * 64 + tx * 4 + e;
                float ek = e2[k];
#pragma unroll
                for (int a = 0; a < 2; ++a)
#pragma unroll
                    for (int b = 0; b < 4; ++b) {
                        float s = ek - 2.f * acc[a][b][c][e];
                        if (s < bv[a][b]) { bv[a][b] = s; bi[a][b] = k; }
                    }
            }
    }
    __syncthreads();
#pragma unroll
    for (int a = 0; a < 2; ++a)
#pragma unroll
        for (int b = 0; b < 4; ++b) {
            int row = a * 64 + ty * 4 + b;
            sh.r.v[row][tx] = bv[a][b]; sh.r.i[row][tx] = bi[a][b];
        }
    __syncthreads();
    if (tid < TMF) {
        float best = sh.r.v[tid][0]; int idx = sh.r.i[tid][0];
#pragma unroll
        for (int j = 1; j < 16; ++j) {
            float v = sh.r.v[tid][j]; int ii = sh.r.i[tid][j];
            if (v < best || (v == best && ii < idx)) { best = v; idx = ii; }
        }
        bestv[(size_t)blockIdx.y * NTOK + m0 + tid] = best;
        besti[(size_t)blockIdx.y * NTOK + m0 + tid] = idx;
    }
}

__global__ __launch_bounds__(256) void vq_gather_fp32(
        const float* __restrict__ embed, const float* __restrict__ bestv,
        const int* __restrict__ besti, float* __restrict__ out) {
    int token = blockIdx.x * 4 + (threadIdx.x >> 6);
    int lane = threadIdx.x & 63;
    float best = bestv[token]; int idx = besti[token];
#pragma unroll
    for (int s = 1; s < KSPLITF; ++s) {
        float v = bestv[(size_t)s * NTOK + token];
        int ii = besti[(size_t)s * NTOK + token];
        if (v < best || (v == best && ii < idx)) { best = v; idx = ii; }
    }
    const float4* src = (const float4*)(embed + (size_t)idx * DDIM);
    float4* dst = (float4*)(out + (size_t)token * DDIM);
    dst[lane] = src[lane];
}

// ===========================================================================
extern "C" void kernel_launch(void* const* d_in, const int* in_sizes, int n_in,
                              void* d_out, int out_size, void* d_ws, size_t ws_size,
                              hipStream_t stream) {
    (void)in_sizes; (void)n_in; (void)out_size;
    const float* x = (const float*)d_in[0];
    const float* embed = (const float*)d_in[1];
    float* out = (float*)d_out;

    char* w = (char*)d_ws;
    auto carve = [&](size_t bytes) { char* p = w; w += (bytes + 255) & ~(size_t)255; return p; };

    const size_t sz_eh = (size_t)KCB * DDIM * 2;           // 2 MB
    const size_t need = 2 * sz_eh + KCB * 4 + 3 * (size_t)NTOK * NSA * 4 +
                        (size_t)XCAP * 4 + 2 * (size_t)XCAP * NST * 4 + 8192;

    if (ws_size >= need) {
        ushort_t* eh = (ushort_t*)carve(sz_eh);
        ushort_t* el = (ushort_t*)carve(sz_eh);
        float* cc = (float*)carve(KCB * 4);
        float* gv1 = (float*)carve((size_t)NTOK * NSA * 4);
        int* gi1 = (int*)carve((size_t)NTOK * NSA * 4);
        float* gv2 = (float*)carve((size_t)NTOK * NSA * 4);
        int* wl = (int*)carve((size_t)XCAP * 4);
        float* rv = (float*)carve((size_t)XCAP * NST * 4);
        int* ri = (int*)carve((size_t)XCAP * NST * 4);
        int* count = (int*)carve(256);

        vq_convert_e<<<KCB / 4, 256, 0, stream>>>(embed, eh, el, cc, count);
        vq_pass_a<<<dim3(NTOK / 128, NSA), 256, 0, stream>>>(x, eh, cc, gv1, gi1, gv2);
        vq_merge_gather<<<NTOK / 4, 256, 0, stream>>>(gv1, gi1, gv2, embed, out, wl, count);
        vq_rescore_mfma<<<dim3(XCAP / 64, NST), 256, 0, stream>>>(
            x, eh, el, cc, wl, count, rv, ri);
        vq_merge2_gather<<<XCAP / 4, 256, 0, stream>>>(wl, count, rv, ri, embed, out);
    } else {
        float* e2 = (float*)carve(KCB * 4);
        float* bestv = (float*)carve((size_t)KSPLITF * NTOK * 4);
        int* besti = (int*)carve((size_t)KSPLITF * NTOK * 4);
        vq_e2_fp32<<<KCB / 256, 256, 0, stream>>>(embed, e2);
        vq_main_fp32<<<dim3(NTOK / TMF, KSPLITF), 256, 0, stream>>>(x, embed, e2, bestv, besti);
        vq_gather_fp32<<<NTOK / 4, 256, 0, stream>>>(embed, bestv, besti, out);
    }
}

// Round 9
// 277.583 us; speedup vs baseline: 1.4806x; 1.3926x over previous
//
#include <hip/hip_runtime.h>
#include <cstdint>

#define NTOK 32768
#define DDIM 256
#define KCB  4096
#define NSA 4            // n-splits in pass A (1024 codes per block)
#define NST 8            // n-splits in tier-2 (512 codes per block)
#define XCAP 8192        // max flagged tokens
#define MARGIN_U 0.0625f // on u = dot + cc (validated r7/r8)

typedef _Float16 half8 __attribute__((ext_vector_type(8)));
typedef float f32x4 __attribute__((ext_vector_type(4)));
typedef unsigned short ushort_t;

// ---------------------------------------------------------------------------
// helpers
// ---------------------------------------------------------------------------
__device__ __forceinline__ ushort_t f2h(float f, float& back) {
    _Float16 h = (_Float16)f;
    back = (float)h;
    union { _Float16 h; ushort_t u; } c; c.h = h; return c.u;
}
__device__ __forceinline__ short h2s(_Float16 h) {
    union { _Float16 h; short s; } c; c.h = h; return c.s;
}
__device__ __forceinline__ void gload_lds16(const void* g, void* l) {
    __builtin_amdgcn_global_load_lds(
        (const __attribute__((address_space(1))) void*)g,
        (__attribute__((address_space(3))) void*)l, 16, 0, 0);
}

// ---------------------------------------------------------------------------
// convert embed -> f16 hi/lo + cc[k] = 512 - 0.5*e2[k]; zero worklist counter
// ---------------------------------------------------------------------------
__global__ __launch_bounds__(256) void vq_convert_e(
        const float* __restrict__ embed, ushort_t* __restrict__ hi,
        ushort_t* __restrict__ lo, float* __restrict__ cc,
        int* __restrict__ count) {
    if (blockIdx.x == 0 && threadIdx.x == 0) *count = 0;
    int row = blockIdx.x * 4 + (threadIdx.x >> 6);
    int lane = threadIdx.x & 63;
    size_t off = (size_t)row * DDIM + lane * 4;
    float4 v = *(const float4*)(embed + off);
    float bx, by, bz, bw;
    ushort4 h, l;
    h.x = f2h(v.x, bx); h.y = f2h(v.y, by); h.z = f2h(v.z, bz); h.w = f2h(v.w, bw);
    float t;
    l.x = f2h(v.x - bx, t); l.y = f2h(v.y - by, t);
    l.z = f2h(v.z - bz, t); l.w = f2h(v.w - bw, t);
    *(ushort4*)(hi + off) = h;
    *(ushort4*)(lo + off) = l;
    float s = v.x * v.x + v.y * v.y + v.z * v.z + v.w * v.w;
#pragma unroll
    for (int o = 1; o < 64; o <<= 1) s += __shfl_xor(s, o, 64);
    if (lane == 0) cc[row] = 512.f - 0.5f * s;
}

// ---------------------------------------------------------------------------
// Pass A (r4 skeleton + partial register-A):
// 128 tokens x 1024 codes, grid (256, 4). A (x->f16) staged once into 64 KB
// LDS; A-frags for kk=0..3 then promoted to 64 persistent VGPRs (all indices
// compile-time -> stays in registers), kk=4..7 read from LDS. B staged via
// global_load_lds double-buffer, ONE barrier per kk-step (proven m97-style).
// Epilogue: 5-bit packed-index tournament top-2 of u = dot + cc.
// ---------------------------------------------------------------------------
__global__ __launch_bounds__(256, 2) void vq_pass_a(
        const float* __restrict__ x, const ushort_t* __restrict__ eh,
        const float* __restrict__ cc,
        float* __restrict__ gv1, int* __restrict__ gi1, float* __restrict__ gv2) {
    __shared__ union U {
        struct { short A[8][128][32]; short B[2][128][32]; } t;   // 64 + 16 KB
        struct { float v1[128][2]; int i1[128][2]; float v2[128][2]; } r;
    } sh;
    const int tid = threadIdx.x;
    const int m0 = blockIdx.x * 128;
    const int kbase = blockIdx.y * (KCB / NSA);
    const int lane = tid & 63, wv = tid >> 6, wr = wv >> 1, wc = wv & 1;
    const int L15 = lane & 15, quad = lane >> 4;

    // ---- B staging mapping (global_load_lds width 16, r4-proven) ----
    const int ca0 = tid, ca1 = 256 + tid;
    const int brow0 = ca0 >> 2, bq0 = ca0 & 3;
    const int brow1 = ca1 >> 2, bq1 = ca1 & 3;
    const ushort_t* ebase = eh + (size_t)kbase * DDIM;
    auto stageB = [&](int it) {      // it in [0, 64)
        int nt = it >> 3, kk = it & 7;
        short* base = &sh.t.B[it & 1][0][0];
        gload_lds16(ebase + (size_t)(nt * 128 + brow0) * DDIM + kk * 32 + bq0 * 8, base + ca0 * 8);
        gload_lds16(ebase + (size_t)(nt * 128 + brow1) * DDIM + kk * 32 + bq1 * 8, base + ca1 * 8);
    };
    stageB(0);

    // ---- stage A once: x fp32 -> f16 into LDS ----
    {
        const int fr = tid >> 6;          // 0..3
        const int f = tid & 63;           // float4 index within row
        const int akk = f >> 3, aoff = (f & 7) * 4;
#pragma unroll 8
        for (int s = 0; s < 32; ++s) {
            int row = s * 4 + fr;
            float4 v = *(const float4*)(x + (size_t)(m0 + row) * DDIM + f * 4);
            short4 pk = { h2s((_Float16)v.x), h2s((_Float16)v.y),
                          h2s((_Float16)v.z), h2s((_Float16)v.w) };
            *(short4*)(&sh.t.A[akk][row][aoff]) = pk;
        }
    }
    __syncthreads();

    // ---- promote A-frags kk=0..3 to registers (fully unrolled, const idx) ----
    half8 Areg[4][4];
#pragma unroll
    for (int kk = 0; kk < 4; ++kk)
#pragma unroll
        for (int i = 0; i < 4; ++i)
            Areg[kk][i] = *(const half8*)(&sh.t.A[kk][wr * 64 + i * 16 + L15][quad * 8]);

    const float* pc = cc + kbase + wc * 64 + L15;
    float v1p[16], v2p[16];
#pragma unroll
    for (int s = 0; s < 16; ++s) { v1p[s] = -3.4e38f; v2p[s] = -3.4e38f; }

    f32x4 acc[4][4];
#pragma unroll 1
    for (int nt = 0; nt < 8; ++nt) {
        float cc0 = pc[0], cc1 = pc[16], cc2 = pc[32], cc3 = pc[48];
        pc += 128;
#pragma unroll
        for (int kk = 0; kk < 8; ++kk) {
            const int it = nt * 8 + kk;
            __syncthreads();              // drains stage(it) issued one phase ago
            if (it + 1 < 64) stageB(it + 1);
            const short* Bf = &sh.t.B[it & 1][0][0] + (wc * 64 + L15) * 32 + quad * 8;
            half8 a0, a1, a2, a3;
            if (kk < 4) {                 // kk is a compile-time constant here
                a0 = Areg[kk][0]; a1 = Areg[kk][1];
                a2 = Areg[kk][2]; a3 = Areg[kk][3];
            } else {
                const short* Af = &sh.t.A[kk][wr * 64 + L15][quad * 8];
                a0 = *(const half8*)(Af);
                a1 = *(const half8*)(Af + 16 * 32);
                a2 = *(const half8*)(Af + 32 * 32);
                a3 = *(const half8*)(Af + 48 * 32);
            }
#pragma unroll
            for (int j = 0; j < 4; ++j) {
                half8 bj = *(const half8*)(Bf + j * 16 * 32);
                if (kk == 0) {
                    acc[0][j] = __builtin_amdgcn_mfma_f32_16x16x32_f16(a0, bj, (f32x4){0.f,0.f,0.f,0.f}, 0, 0, 0);
                    acc[1][j] = __builtin_amdgcn_mfma_f32_16x16x32_f16(a1, bj, (f32x4){0.f,0.f,0.f,0.f}, 0, 0, 0);
                    acc[2][j] = __builtin_amdgcn_mfma_f32_16x16x32_f16(a2, bj, (f32x4){0.f,0.f,0.f,0.f}, 0, 0, 0);
                    acc[3][j] = __builtin_amdgcn_mfma_f32_16x16x32_f16(a3, bj, (f32x4){0.f,0.f,0.f,0.f}, 0, 0, 0);
                } else {
                    acc[0][j] = __builtin_amdgcn_mfma_f32_16x16x32_f16(a0, bj, acc[0][j], 0, 0, 0);
                    acc[1][j] = __builtin_amdgcn_mfma_f32_16x16x32_f16(a1, bj, acc[1][j], 0, 0, 0);
                    acc[2][j] = __builtin_amdgcn_mfma_f32_16x16x32_f16(a2, bj, acc[2][j], 0, 0, 0);
                    acc[3][j] = __builtin_amdgcn_mfma_f32_16x16x32_f16(a3, bj, acc[3][j], 0, 0, 0);
                }
            }
        }
        // 5-bit packed-index tournament top-2 of u = dot + cc (u > 0 always)
        const unsigned inv0 = (unsigned)(31 - nt * 4);
#pragma unroll
        for (int i = 0; i < 4; ++i)
#pragma unroll
            for (int r = 0; r < 4; ++r) {
                const int slot = i * 4 + r;
                float u0 = acc[i][0][r] + cc0;
                float u1 = acc[i][1][r] + cc1;
                float u2 = acc[i][2][r] + cc2;
                float u3 = acc[i][3][r] + cc3;
                float p0 = __uint_as_float((__float_as_uint(u0) & 0xFFFFFFE0u) | inv0);
                float p1 = __uint_as_float((__float_as_uint(u1) & 0xFFFFFFE0u) | (inv0 - 1));
                float p2 = __uint_as_float((__float_as_uint(u2) & 0xFFFFFFE0u) | (inv0 - 2));
                float p3 = __uint_as_float((__float_as_uint(u3) & 0xFFFFFFE0u) | (inv0 - 3));
                float h1 = fmaxf(p0, p1), l1 = fminf(p0, p1);
                float h2 = fmaxf(p2, p3), l2 = fminf(p2, p3);
                float m1 = fmaxf(h1, h2);
                float mm = fminf(h1, h2);
                float m2 = fmaxf(fmaxf(mm, l1), l2);         // v_max3
                float t = fminf(v1p[slot], m1);
                v1p[slot] = fmaxf(v1p[slot], m1);
                v2p[slot] = fmaxf(fmaxf(v2p[slot], t), m2);  // v_max3
            }
    }

    __syncthreads();   // done with sh.t before reduction reuse
#pragma unroll
    for (int i = 0; i < 4; ++i)
#pragma unroll
        for (int r = 0; r < 4; ++r) {
            const int slot = i * 4 + r;
            unsigned b1 = __float_as_uint(v1p[slot]);
            int lin = 31 - (int)(b1 & 31u);
            float a1 = v1p[slot];
            int ai = kbase + (lin >> 2) * 128 + wc * 64 + (lin & 3) * 16 + L15;
            float a2 = v2p[slot];
#pragma unroll
            for (int off = 1; off < 16; off <<= 1) {
                float o1 = __shfl_xor(a1, off, 64);
                int oi = __shfl_xor(ai, off, 64);
                float o2 = __shfl_xor(a2, off, 64);
                if (o1 > a1 || (o1 == a1 && oi < ai)) {
                    a2 = fmaxf(a1, o2); a1 = o1; ai = oi;
                } else {
                    a2 = fmaxf(a2, o1);
                }
            }
            if (L15 == 0) {
                int lr = wr * 64 + i * 16 + quad * 4 + r;
                sh.r.v1[lr][wc] = a1; sh.r.i1[lr][wc] = ai; sh.r.v2[lr][wc] = a2;
            }
        }
    __syncthreads();
    if (tid < 128) {
        float av1 = sh.r.v1[tid][0]; int ai1 = sh.r.i1[tid][0]; float av2 = sh.r.v2[tid][0];
        float bv1 = sh.r.v1[tid][1]; int bi1 = sh.r.i1[tid][1]; float bv2 = sh.r.v2[tid][1];
        float o1, o2; int oi;
        if (bv1 > av1 || (bv1 == av1 && bi1 < ai1)) { o1 = bv1; oi = bi1; o2 = fmaxf(av1, bv2); }
        else { o1 = av1; oi = ai1; o2 = fmaxf(av2, bv1); }
        size_t o = (size_t)(m0 + tid) * NSA + blockIdx.y;
        gv1[o] = o1; gi1[o] = oi; gv2[o] = o2;
    }
}

// ---------------------------------------------------------------------------
// merge NSA slices per token; gather clear winners; flag small-gap tokens
// ---------------------------------------------------------------------------
__global__ __launch_bounds__(256) void vq_merge_gather(
        const float* __restrict__ gv1, const int* __restrict__ gi1,
        const float* __restrict__ gv2, const float* __restrict__ embed,
        float* __restrict__ out, int* __restrict__ wl, int* __restrict__ count) {
    int wave = threadIdx.x >> 6, lane = threadIdx.x & 63;
    int t = blockIdx.x * 4 + wave;
    float v1 = -3.4e38f, v2 = -3.4e38f; int i1 = 0x7fffffff;
    if (lane < NSA) {
        size_t o = (size_t)t * NSA + lane;
        v1 = gv1[o]; i1 = gi1[o]; v2 = gv2[o];
    }
#pragma unroll
    for (int off = 1; off < NSA; off <<= 1) {
        float o1 = __shfl_xor(v1, off, 64);
        int oi = __shfl_xor(i1, off, 64);
        float o2 = __shfl_xor(v2, off, 64);
        if (o1 > v1 || (o1 == v1 && oi < i1)) { v2 = fmaxf(v1, o2); v1 = o1; i1 = oi; }
        else v2 = fmaxf(v2, o1);
    }
    int flag = __shfl((v1 - v2 < MARGIN_U) ? 1 : 0, 0, 64);
    int idx = __shfl(i1, 0, 64);
    int p = 0x7fffffff;
    if (flag && lane == 0) p = atomicAdd(count, 1);
    p = __shfl(p, 0, 64);
    if (flag && p < XCAP) {
        if (lane == 0) wl[p] = t;
    } else {
        const float4* src = (const float4*)(embed + (size_t)idx * DDIM);
        float4* dst = (float4*)(out + (size_t)t * DDIM);
        dst[lane] = src[lane];
    }
}

// ---------------------------------------------------------------------------
// Tier-2: 3-pass f16 MFMA rescore, barrier-free K-loop (validated r5-r8).
// Block: 64 flagged tokens x 512 codes (NST=8).
// ---------------------------------------------------------------------------
__global__ __launch_bounds__(256, 2) void vq_rescore_mfma(
        const float* __restrict__ x, const ushort_t* __restrict__ eh,
        const ushort_t* __restrict__ el, const float* __restrict__ cc,
        const int* __restrict__ wl, const int* __restrict__ count,
        float* __restrict__ rv, int* __restrict__ ri) {
    const int cnt = min(*count, XCAP);
    const int m0 = blockIdx.x * 64;
    if (m0 >= cnt) return;
    __shared__ union U {
        struct { short Ah[8][64][32]; short Al[8][64][32]; } t;   // 32+32 KB
        struct { float v1[64][2]; int i1[64][2]; } r;
    } sh;
    const int tid = threadIdx.x;
    const int lane = tid & 63, wv = tid >> 6, wr = wv >> 1, wc = wv & 1;
    const int L15 = lane & 15, quad = lane >> 4;

    // ---- stage A (hi+lo) once ----
    {
        const int fr = tid >> 6;
        const int f = tid & 63;
        const int akk = f >> 3, aoff = (f & 7) * 4;
#pragma unroll 4
        for (int s = 0; s < 16; ++s) {
            int row = s * 4 + fr;
            int t = wl[min(m0 + row, cnt - 1)];
            float4 v = *(const float4*)(x + (size_t)t * DDIM + f * 4);
            float bx, by, bz, bw;
            short4 ph = { (short)f2h(v.x, bx), (short)f2h(v.y, by),
                          (short)f2h(v.z, bz), (short)f2h(v.w, bw) };
            float tt;
            short4 pl = { (short)f2h(v.x - bx, tt), (short)f2h(v.y - by, tt),
                          (short)f2h(v.z - bz, tt), (short)f2h(v.w - bw, tt) };
            *(short4*)(&sh.t.Ah[akk][row][aoff]) = ph;
            *(short4*)(&sh.t.Al[akk][row][aoff]) = pl;
        }
    }
    __syncthreads();

    const unsigned obase = (unsigned)((wc * 64 + L15) * DDIM + quad * 8);
    const unsigned nbase = (unsigned)(blockIdx.y * (KCB / NST) * DDIM);

    float v1[8]; int i1[8];
#pragma unroll
    for (int s = 0; s < 8; ++s) { v1[s] = -3.4e38f; i1[s] = 0; }

#pragma unroll 1
    for (int nt = 0; nt < 4; ++nt) {
        f32x4 acc[2][4];
#pragma unroll 1
        for (int ph = 0; ph < 3; ++ph) {
            const short (*As)[64][32] = (ph < 2) ? sh.t.Ah : sh.t.Al;
            const ushort_t* Bs = (ph == 1) ? el : eh;
            auto loadA = [&](int kk, half8* dst) {
#pragma unroll
                for (int i = 0; i < 2; ++i)
                    dst[i] = *(const half8*)(&As[kk][wr * 32 + i * 16 + L15][quad * 8]);
            };
            auto loadB = [&](int kk, half8* dst) {
                unsigned o = nbase + obase + (unsigned)(nt * 128 * DDIM + kk * 32);
#pragma unroll
                for (int j = 0; j < 4; ++j)
                    dst[j] = *(const half8*)(Bs + o + j * 16 * DDIM);
            };
            half8 a[2][2], b[2][4];
            loadA(0, a[0]); loadB(0, b[0]);
#pragma unroll
            for (int kk = 0; kk < 8; ++kk) {
                const int cur = kk & 1, nxt = cur ^ 1;
                if (kk < 7) { loadB(kk + 1, b[nxt]); loadA(kk + 1, a[nxt]); }
#pragma unroll
                for (int i = 0; i < 2; ++i)
#pragma unroll
                    for (int j = 0; j < 4; ++j) {
                        if (ph == 0 && kk == 0)
                            acc[i][j] = __builtin_amdgcn_mfma_f32_16x16x32_f16(
                                a[cur][i], b[cur][j], (f32x4){0.f, 0.f, 0.f, 0.f}, 0, 0, 0);
                        else
                            acc[i][j] = __builtin_amdgcn_mfma_f32_16x16x32_f16(
                                a[cur][i], b[cur][j], acc[i][j], 0, 0, 0);
                    }
            }
        }
        const int nb = blockIdx.y * (KCB / NST) + nt * 128 + wc * 64 + L15;
#pragma unroll
        for (int j = 0; j < 4; ++j) {
            float ccv = cc[nb + j * 16];
#pragma unroll
            for (int i = 0; i < 2; ++i)
#pragma unroll
                for (int r = 0; r < 4; ++r) {
                    const int slot = i * 4 + r;
                    float u = acc[i][j][r] + ccv;
                    int n = nb + j * 16;
                    if (u > v1[slot]) { v1[slot] = u; i1[slot] = n; }
                }
        }
    }
    __syncthreads();
#pragma unroll
    for (int i = 0; i < 2; ++i)
#pragma unroll
        for (int r = 0; r < 4; ++r) {
            const int slot = i * 4 + r;
            float a1 = v1[slot]; int ai = i1[slot];
#pragma unroll
            for (int off = 1; off < 16; off <<= 1) {
                float o1 = __shfl_xor(a1, off, 64);
                int oi = __shfl_xor(ai, off, 64);
                if (o1 > a1 || (o1 == a1 && oi < ai)) { a1 = o1; ai = oi; }
            }
            if (L15 == 0) {
                int lr = wr * 32 + i * 16 + quad * 4 + r;
                sh.r.v1[lr][wc] = a1; sh.r.i1[lr][wc] = ai;
            }
        }
    __syncthreads();
    if (tid < 64 && m0 + tid < cnt) {
        float av1 = sh.r.v1[tid][0]; int ai1 = sh.r.i1[tid][0];
        float bv1 = sh.r.v1[tid][1]; int bi1 = sh.r.i1[tid][1];
        float o1; int oi;
        if (bv1 > av1 || (bv1 == av1 && bi1 < ai1)) { o1 = bv1; oi = bi1; }
        else { o1 = av1; oi = ai1; }
        size_t o = (size_t)(m0 + tid) * NST + blockIdx.y;
        rv[o] = o1; ri[o] = oi;
    }
}

// ---------------------------------------------------------------------------
// merge tier-2 slices + gather for flagged tokens (one wave per token)
// ---------------------------------------------------------------------------
__global__ __launch_bounds__(256) void vq_merge2_gather(
        const int* __restrict__ wl, const int* __restrict__ count,
        const float* __restrict__ rv, const int* __restrict__ ri,
        const float* __restrict__ embed, float* __restrict__ out) {
    int wave = threadIdx.x >> 6, lane = threadIdx.x & 63;
    int wi = blockIdx.x * 4 + wave;
    int cnt = min(*count, XCAP);
    if (wi >= cnt) return;
    float v1 = -3.4e38f; int i1 = 0x7fffffff;
    if (lane < NST) {
        size_t o = (size_t)wi * NST + lane;
        v1 = rv[o]; i1 = ri[o];
    }
#pragma unroll
    for (int off = 1; off < NST; off <<= 1) {
        float o1 = __shfl_xor(v1, off, 64);
        int oi = __shfl_xor(i1, off, 64);
        if (o1 > v1 || (o1 == v1 && oi < i1)) { v1 = o1; i1 = oi; }
    }
    int idx = __shfl(i1, 0, 64);
    int t = wl[wi];
    const float4* src = (const float4*)(embed + (size_t)idx * DDIM);
    float4* dst = (float4*)(out + (size_t)t * DDIM);
    dst[lane] = src[lane];
}

// ===========================================================================
// Fallback fp32 path (round-1, validated) for small workspace
// ===========================================================================
#define TMF 128
#define DCF 32
#define LSF 132
#define KSPLITF 4
#define KPERF (KCB / KSPLITF)

__global__ __launch_bounds__(256) void vq_e2_fp32(const float* __restrict__ embed,
                                                  float* __restrict__ e2) {
    int k = blockIdx.x * blockDim.x + threadIdx.x;
    if (k >= KCB) return;
    const float4* row = (const float4*)(embed + (size_t)k * DDIM);
    float s = 0.f;
#pragma unroll
    for (int i = 0; i < DDIM / 4; ++i) {
        float4 v = row[i];
        s += v.x * v.x + v.y * v.y + v.z * v.z + v.w * v.w;
    }
    e2[k] = s;
}

__global__ __launch_bounds__(256, 3) void vq_main_fp32(
        const float* __restrict__ x, const float* __restrict__ embed,
        const float* __restrict__ e2,
        float* __restrict__ bestv, int* __restrict__ besti) {
    __shared__ union U {
        struct { float xs[DCF][LSF]; float es[DCF][LSF]; } t;
        struct { float v[TMF][16]; int i[TMF][16]; } r;
    } sh;
    const int tid = threadIdx.x;
    const int tx = tid & 15, ty = tid >> 4;
    const int m0 = blockIdx.x * TMF;
    const int kbase = blockIdx.y * KPERF;
    const int srow = tid >> 3, sd4 = (tid & 7) * 4;
    float bv[2][4]; int bi[2][4];
#pragma unroll
    for (int a = 0; a < 2; ++a)
#pragma unroll
        for (int b = 0; b < 4; ++b) { bv[a][b] = 3.4e38f; bi[a][b] = 0; }
    for (int kt = 0; kt < KPERF / 128; ++kt) {
        const int k0 = kbase + kt * 128;
        float acc[2][4][2][4];
#pragma unroll
        for (int a = 0; a < 2; ++a)
#pragma unroll
            for (int b = 0; b < 4; ++b)
#pragma unroll
                for (int c = 0; c < 2; ++c)
#pragma unroll
                    for (int e = 0; e < 4; ++e) acc[a][b][c][e] = 0.f;
        for (int dc = 0; dc < DDIM / DCF; ++dc) {
#pragma unroll
            for (int p = 0; p < 4; ++p) {
                int m = p * 32 + srow;
                float4 v = *(const float4*)(x + (size_t)(m0 + m) * DDIM + dc * DCF + sd4);
                sh.t.xs[sd4 + 0][m] = v.x; sh.t.xs[sd4 + 1][m] = v.y;
                sh.t.xs[sd4 + 2][m] = v.z; sh.t.xs[sd4 + 3][m] = v.w;
                float4 w = *(const float4*)(embed + (size_t)(k0 + m) * DDIM + dc * DCF + sd4);
                sh.t.es[sd4 + 0][m] = w.x; sh.t.es[sd4 + 1][m] = w.y;
                sh.t.es[sd4 + 2][m] = w.z; sh.t.es[sd4 + 3][m] = w.w;
            }
            __syncthreads();
#pragma unroll 8
            for (int d = 0; d < DCF; ++d) {
                float4 xa0 = *(const float4*)&sh.t.xs[d][ty * 4];
                float4 xa1 = *(const float4*)&sh.t.xs[d][ty * 4 + 64];
                float4 eb0 = *(const float4*)&sh.t.es[d][tx * 4];
                float4 eb1 = *(const float4*)&sh.t.es[d][tx * 4 + 64];
                float xr[2][4] = {{xa0.x, xa0.y, xa0.z, xa0.w}, {xa1.x, xa1.y, xa1.z, xa1.w}};
                float er[2][4] = {{eb0.x, eb0.y, eb0.z, eb0.w}, {eb1.x, eb1.y, eb1.z, eb1.w}};
#pragma unroll
                for (int a = 0; a < 2; ++a)
#pragma unroll
                    for (int b = 0; b < 4; ++b)
#pragma unroll
                        for (int c = 0; c < 2; ++c)
#pragma unroll
                            for (int e = 0; e < 4; ++e)
                                acc[a][b][c][e] += xr[a][b] * er[c][e];
            }
            __syncthreads();
        }
#pragma unroll
        for (int c = 0; c < 2; ++c)
#pragma unroll
            for (int e = 0; e < 4; ++e) {
                int k = k0 + c * 64 + tx * 4 + e;
                float ek = e2[k];
#pragma unroll
                for (int a = 0; a < 2; ++a)
#pragma unroll
                    for (int b = 0; b < 4; ++b) {
                        float s = ek - 2.f * acc[a][b][c][e];
                        if (s < bv[a][b]) { bv[a][b] = s; bi[a][b] = k; }
                    }
            }
    }
    __syncthreads();
#pragma unroll
    for (int a = 0; a < 2; ++a)
#pragma unroll
        for (int b = 0; b < 4; ++b) {
            int row = a * 64 + ty * 4 + b;
            sh.r.v[row][tx] = bv[a][b]; sh.r.i[row][tx] = bi[a][b];
        }
    __syncthreads();
    if (tid < TMF) {
        float best = sh.r.v[tid][0]; int idx = sh.r.i[tid][0];
#pragma unroll
        for (int j = 1; j < 16; ++j) {
            float v = sh.r.v[tid][j]; int ii = sh.r.i[tid][j];
            if (v < best || (v == best && ii < idx)) { best = v; idx = ii; }
        }
        bestv[(size_t)blockIdx.y * NTOK + m0 + tid] = best;
        besti[(size_t)blockIdx.y * NTOK + m0 + tid] = idx;
    }
}

__global__ __launch_bounds__(256) void vq_gather_fp32(
        const float* __restrict__ embed, const float* __restrict__ bestv,
        const int* __restrict__ besti, float* __restrict__ out) {
    int token = blockIdx.x * 4 + (threadIdx.x >> 6);
    int lane = threadIdx.x & 63;
    float best = bestv[token]; int idx = besti[token];
#pragma unroll
    for (int s = 1; s < KSPLITF; ++s) {
        float v = bestv[(size_t)s * NTOK + token];
        int ii = besti[(size_t)s * NTOK + token];
        if (v < best || (v == best && ii < idx)) { best = v; idx = ii; }
    }
    const float4* src = (const float4*)(embed + (size_t)idx * DDIM);
    float4* dst = (float4*)(out + (size_t)token * DDIM);
    dst[lane] = src[lane];
}

// ===========================================================================
extern "C" void kernel_launch(void* const* d_in, const int* in_sizes, int n_in,
                              void* d_out, int out_size, void* d_ws, size_t ws_size,
                              hipStream_t stream) {
    (void)in_sizes; (void)n_in; (void)out_size;
    const float* x = (const float*)d_in[0];
    const float* embed = (const float*)d_in[1];
    float* out = (float*)d_out;

    char* w = (char*)d_ws;
    auto carve = [&](size_t bytes) { char* p = w; w += (bytes + 255) & ~(size_t)255; return p; };

    const size_t sz_eh = (size_t)KCB * DDIM * 2;           // 2 MB
    const size_t need = 2 * sz_eh + KCB * 4 + 3 * (size_t)NTOK * NSA * 4 +
                        (size_t)XCAP * 4 + 2 * (size_t)XCAP * NST * 4 + 8192;

    if (ws_size >= need) {
        ushort_t* eh = (ushort_t*)carve(sz_eh);
        ushort_t* el = (ushort_t*)carve(sz_eh);
        float* cc = (float*)carve(KCB * 4);
        float* gv1 = (float*)carve((size_t)NTOK * NSA * 4);
        int* gi1 = (int*)carve((size_t)NTOK * NSA * 4);
        float* gv2 = (float*)carve((size_t)NTOK * NSA * 4);
        int* wl = (int*)carve((size_t)XCAP * 4);
        float* rv = (float*)carve((size_t)XCAP * NST * 4);
        int* ri = (int*)carve((size_t)XCAP * NST * 4);
        int* count = (int*)carve(256);

        vq_convert_e<<<KCB / 4, 256, 0, stream>>>(embed, eh, el, cc, count);
        vq_pass_a<<<dim3(NTOK / 128, NSA), 256, 0, stream>>>(x, eh, cc, gv1, gi1, gv2);
        vq_merge_gather<<<NTOK / 4, 256, 0, stream>>>(gv1, gi1, gv2, embed, out, wl, count);
        vq_rescore_mfma<<<dim3(XCAP / 64, NST), 256, 0, stream>>>(
            x, eh, el, cc, wl, count, rv, ri);
        vq_merge2_gather<<<XCAP / 4, 256, 0, stream>>>(wl, count, rv, ri, embed, out);
    } else {
        float* e2 = (float*)carve(KCB * 4);
        float* bestv = (float*)carve((size_t)KSPLITF * NTOK * 4);
        int* besti = (int*)carve((size_t)KSPLITF * NTOK * 4);
        vq_e2_fp32<<<KCB / 256, 256, 0, stream>>>(embed, e2);
        vq_main_fp32<<<dim3(NTOK / TMF, KSPLITF), 256, 0, stream>>>(x, embed, e2, bestv, besti);
        vq_gather_fp32<<<NTOK / 4, 256, 0, stream>>>(embed, bestv, besti, out);
    }
}